// Round 2
// baseline (408.633 us; speedup 1.0000x reference)
//
#include <hip/hip_runtime.h>
#include <hip/hip_bf16.h>

#define N_NODES 140000
#define N_EDGES 2240000
#define NFEAT 128
#define NHID 128
#define N_FRAMES 14
#define NODES_PER_FRAME 10000

typedef __attribute__((ext_vector_type(8))) short frag_b16;
typedef __attribute__((ext_vector_type(4))) int frag_i4;
typedef __attribute__((ext_vector_type(4))) float f32x4;

__device__ __forceinline__ unsigned short f2bf(float f) {
    union { float f; unsigned int u; } v; v.f = f;
    unsigned int r = v.u + 0x7fffu + ((v.u >> 16) & 1u);   // RNE
    return (unsigned short)(r >> 16);
}
__device__ __forceinline__ float bf2f(unsigned short h) {
    union { unsigned int u; float f; } v; v.u = ((unsigned int)h) << 16;
    return v.f;
}
__device__ __forceinline__ int pk_bf16(float a, float b) {
    union { __hip_bfloat162 h; int i; } u;
    u.h = __float22bfloat162_rn(make_float2(a, b));        // v_cvt_pk_bf16_f32
    return u.i;
}

// ---------------------------------------------------------------------------
// Prep 1: WT_bf16[n*128 + k] = bf16(W[k*128 + n])   (transpose + convert)
// ---------------------------------------------------------------------------
__global__ void convert_wt(const float* __restrict__ W, unsigned short* __restrict__ WT) {
    int idx = blockIdx.x * blockDim.x + threadIdx.x;
    if (idx >= NFEAT * NHID) return;
    int k = idx >> 7, n = idx & 127;
    WT[n * 128 + k] = f2bf(W[idx]);
}

// ---------------------------------------------------------------------------
// Prep 2: CSR row offsets from sorted COO rows (no atomics downstream)
// ---------------------------------------------------------------------------
__global__ void build_row_ptr(const int* __restrict__ edge_row, int* __restrict__ row_ptr) {
    int e = blockIdx.x * blockDim.x + threadIdx.x;
    if (e >= N_EDGES) return;
    int r = edge_row[e];
    int prev = (e == 0) ? -1 : edge_row[e - 1];
    for (int q = prev + 1; q <= r; ++q) row_ptr[q] = e;
    if (e == N_EDGES - 1) {
        for (int q = r + 1; q <= N_NODES; ++q) row_ptr[q] = N_EDGES;
    }
}

// ---------------------------------------------------------------------------
// GEMM: support_bf16 = bf16(x @ W), mfma_f32_16x16x32_bf16, operands SWAPPED
// (A = W^T fragment, B = x fragment) so D = (xW)^T fragment-wise: each lane's
// 4 acc regs are 4 CONSECUTIVE FEATURES of one node -> packed 8B stores.
// Block = 256 thr = 4 waves, 64 nodes/block (16/wave), full 128 features.
// ---------------------------------------------------------------------------
#define WT_STRIDE 136

__global__ __launch_bounds__(256) void gemm_kernel(
        const float* __restrict__ x, const unsigned short* __restrict__ WT,
        unsigned short* __restrict__ support) {
    __shared__ unsigned short wt_lds[128 * WT_STRIDE];

    // stage W^T (bf16) into LDS, 16B chunks
    const uint4* WTv = (const uint4*)WT;               // 2048 uint4
    for (int idx = threadIdx.x; idx < 2048; idx += 256) {
        uint4 d = WTv[idx];
        int elem = idx << 3;                           // ushort index
        int n = elem >> 7, k = elem & 127;
        *(uint4*)&wt_lds[n * WT_STRIDE + k] = d;
    }

    int wave = threadIdx.x >> 6;
    int lane = threadIdx.x & 63;
    int m = lane & 15;                                 // node within 16-tile (N dim)
    int q = lane >> 4;                                 // quad

    long row0 = (long)blockIdx.x * 64 + wave * 16;

    // x fragments (B operand): B[k][n]=x[row0+m][k], k = q*8+j (+32 per ks)
    int arow = (int)row0 + m;
    if (arow >= N_NODES) arow = N_NODES - 1;           // clamp (stores guarded)
    const float* xrow = x + (long)arow * 128 + q * 8;
    frag_b16 xa[4];
#pragma unroll
    for (int ks = 0; ks < 4; ++ks) {
        float4 lo = *(const float4*)(xrow + ks * 32);
        float4 hi = *(const float4*)(xrow + ks * 32 + 4);
        union { frag_b16 f; frag_i4 i; } u;
        u.i[0] = pk_bf16(lo.x, lo.y);
        u.i[1] = pk_bf16(lo.z, lo.w);
        u.i[2] = pk_bf16(hi.x, hi.y);
        u.i[3] = pk_bf16(hi.z, hi.w);
        xa[ks] = u.f;
    }

    __syncthreads();

    if (row0 < N_NODES) {
        f32x4 acc[8];
#pragma unroll
        for (int t = 0; t < 8; ++t) acc[t] = (f32x4){0.f, 0.f, 0.f, 0.f};

#pragma unroll
        for (int t = 0; t < 8; ++t) {
            const unsigned short* bp = &wt_lds[(t * 16 + m) * WT_STRIDE + q * 8];
#pragma unroll
            for (int ks = 0; ks < 4; ++ks) {
                frag_b16 wfrag = *(const frag_b16*)(bp + ks * 32);
                // D[feat][node] tile: A = W^T frag, B = x frag
                acc[t] = __builtin_amdgcn_mfma_f32_16x16x32_bf16(wfrag, xa[ks], acc[t], 0, 0, 0);
            }
        }

        // D: col(lane&15)=node, row(q*4+r)=feature offset within tile t.
        // Lane (m,q), tile t -> features t*16+q*4+{0..3} of node row0+m: 8B store.
        long node = row0 + m;
        if (node < N_NODES) {
            unsigned short* srow = support + node * 128;
#pragma unroll
            for (int t = 0; t < 8; ++t) {
                int2 pk;
                pk.x = pk_bf16(acc[t][0], acc[t][1]);
                pk.y = pk_bf16(acc[t][2], acc[t][3]);
                *(int2*)(srow + t * 16 + q * 4) = pk;
            }
        }
    }
}

// ---------------------------------------------------------------------------
// Fused aggregation: per output node i, ALL 14 frames processed concurrently
// (14 independent gather streams -> ~14 loads in flight per wave), relu+bias,
// running max over frames, log_softmax over 128 features.
// Block = 128 threads (thread = feature), grid = 10000.
// Inactive frames gather a clamped repeat address (L1 hit) with val=0, so
// per-frame summation order is identical to the sequential version.
// ---------------------------------------------------------------------------
__global__ __launch_bounds__(128, 4) void agg_kernel(
        const unsigned short* __restrict__ support, const float* __restrict__ b,
        const float* __restrict__ edge_val, const int* __restrict__ edge_col,
        const int* __restrict__ row_ptr, float* __restrict__ out) {
    int i = blockIdx.x;
    int c = threadIdx.x;
    int lane = c & 63, wid = c >> 6;
    __shared__ float red[4];

    float bc = b[c];

    int e0[N_FRAMES], len[N_FRAMES];
    float acc[N_FRAMES];
    int maxE = 0;
#pragma unroll
    for (int f = 0; f < N_FRAMES; ++f) {
        int n = f * NODES_PER_FRAME + i;
        int a = row_ptr[n];
        int z = row_ptr[n + 1];
        e0[f] = a;
        len[f] = z - a;
        maxE = max(maxE, z - a);
        acc[f] = 0.f;
    }

    for (int s = 0; s < maxE; ++s) {
        int col[N_FRAMES];
        float val[N_FRAMES];
#pragma unroll
        for (int f = 0; f < N_FRAMES; ++f) {
            bool act = s < len[f];
            int off = act ? s : max(len[f] - 1, 0);
            int ec = e0[f] + off;
            col[f] = edge_col[ec];
            val[f] = act ? edge_val[ec] : 0.f;
        }
#pragma unroll
        for (int f = 0; f < N_FRAMES; ++f) {
            float sv = bf2f(support[(col[f] << 7) | c]);
            acc[f] = fmaf(val[f], sv, acc[f]);
        }
    }

    float mx = 0.f;                                    // relu => max >= 0
#pragma unroll
    for (int f = 0; f < N_FRAMES; ++f) {
        float h = acc[f] + bc;
        mx = fmaxf(mx, h > 0.f ? h : 0.f);
    }

    // log_softmax over the 128 features (2 waves)
    float v = mx;
#pragma unroll
    for (int off = 32; off >= 1; off >>= 1) v = fmaxf(v, __shfl_xor(v, off));
    if (lane == 0) red[wid] = v;
    __syncthreads();
    float M = fmaxf(red[0], red[1]);

    float ex = __expf(mx - M);
    float s = ex;
#pragma unroll
    for (int off = 32; off >= 1; off >>= 1) s += __shfl_xor(s, off);
    if (lane == 0) red[2 + wid] = s;
    __syncthreads();
    float S = red[2] + red[3];

    out[(i << 7) | c] = (mx - M) - __logf(S);
}

// ---------------------------------------------------------------------------
extern "C" void kernel_launch(void* const* d_in, const int* in_sizes, int n_in,
                              void* d_out, int out_size, void* d_ws, size_t ws_size,
                              hipStream_t stream) {
    const float* x        = (const float*)d_in[0];
    const float* W        = (const float*)d_in[1];
    const float* b        = (const float*)d_in[2];
    const float* edge_val = (const float*)d_in[3];
    const int*   edge_row = (const int*)d_in[4];
    const int*   edge_col = (const int*)d_in[5];
    float* out = (float*)d_out;

    char* ws = (char*)d_ws;
    unsigned short* support = (unsigned short*)ws;                  // 35,840,000 B
    unsigned short* WT      = (unsigned short*)(ws + 35840000);     //     32,768 B
    int*            row_ptr = (int*)(ws + 35840000 + 32768);        //    560,004 B

    convert_wt<<<64, 256, 0, stream>>>(W, WT);
    build_row_ptr<<<(N_EDGES + 255) / 256, 256, 0, stream>>>(edge_row, row_ptr);
    gemm_kernel<<<(N_NODES + 63) / 64, 256, 0, stream>>>(x, WT, support);
    agg_kernel<<<NODES_PER_FRAME, 128, 0, stream>>>(support, b, edge_val, edge_col, row_ptr, out);
}

// Round 3
// 244.535 us; speedup vs baseline: 1.6711x; 1.6711x over previous
//
#include <hip/hip_runtime.h>
#include <hip/hip_bf16.h>

#define N_NODES 140000
#define N_EDGES 2240000
#define NFEAT 128
#define NHID 128
#define N_FRAMES 14
#define NODES_PER_FRAME 10000
#define CAP 224            // LDS edge slots per wave (7 frames, Poisson(112), 13 sigma)

typedef __attribute__((ext_vector_type(8))) short frag_b16;
typedef __attribute__((ext_vector_type(4))) int frag_i4;
typedef __attribute__((ext_vector_type(4))) float f32x4;

__device__ __forceinline__ unsigned short f2bf(float f) {
    union { float f; unsigned int u; } v; v.f = f;
    unsigned int r = v.u + 0x7fffu + ((v.u >> 16) & 1u);   // RNE
    return (unsigned short)(r >> 16);
}
__device__ __forceinline__ int pk_bf16(float a, float b) {
    union { __hip_bfloat162 h; int i; } u;
    u.h = __float22bfloat162_rn(make_float2(a, b));        // v_cvt_pk_bf16_f32
    return u.i;
}
__device__ __forceinline__ float2 bf2x2(unsigned int u) {
    // low ushort = even feature, high = odd (little-endian)
    union { unsigned int u; float f; } lo, hi;
    lo.u = u << 16;
    hi.u = u & 0xffff0000u;
    return make_float2(lo.f, hi.f);
}

// ---------------------------------------------------------------------------
// Prep 1: WT_bf16[n*128 + k] = bf16(W[k*128 + n])   (transpose + convert)
// ---------------------------------------------------------------------------
__global__ void convert_wt(const float* __restrict__ W, unsigned short* __restrict__ WT) {
    int idx = blockIdx.x * blockDim.x + threadIdx.x;
    if (idx >= NFEAT * NHID) return;
    int k = idx >> 7, n = idx & 127;
    WT[n * 128 + k] = f2bf(W[idx]);
}

// ---------------------------------------------------------------------------
// Prep 2: CSR row offsets from sorted COO rows (no atomics downstream)
// ---------------------------------------------------------------------------
__global__ void build_row_ptr(const int* __restrict__ edge_row, int* __restrict__ row_ptr) {
    int e = blockIdx.x * blockDim.x + threadIdx.x;
    if (e >= N_EDGES) return;
    int r = edge_row[e];
    int prev = (e == 0) ? -1 : edge_row[e - 1];
    for (int q = prev + 1; q <= r; ++q) row_ptr[q] = e;
    if (e == N_EDGES - 1) {
        for (int q = r + 1; q <= N_NODES; ++q) row_ptr[q] = N_EDGES;
    }
}

// ---------------------------------------------------------------------------
// GEMM: support_bf16 = bf16(x @ W), mfma_f32_16x16x32_bf16, operands swapped
// (A = W^T frag, B = x frag) so each lane's 4 acc regs = 4 consecutive
// features of one node -> packed 8B stores.
// ---------------------------------------------------------------------------
#define WT_STRIDE 136

__global__ __launch_bounds__(256) void gemm_kernel(
        const float* __restrict__ x, const unsigned short* __restrict__ WT,
        unsigned short* __restrict__ support) {
    __shared__ unsigned short wt_lds[128 * WT_STRIDE];

    const uint4* WTv = (const uint4*)WT;               // 2048 uint4
    for (int idx = threadIdx.x; idx < 2048; idx += 256) {
        uint4 d = WTv[idx];
        int elem = idx << 3;
        int n = elem >> 7, k = elem & 127;
        *(uint4*)&wt_lds[n * WT_STRIDE + k] = d;
    }

    int wave = threadIdx.x >> 6;
    int lane = threadIdx.x & 63;
    int m = lane & 15;
    int q = lane >> 4;

    long row0 = (long)blockIdx.x * 64 + wave * 16;

    int arow = (int)row0 + m;
    if (arow >= N_NODES) arow = N_NODES - 1;
    const float* xrow = x + (long)arow * 128 + q * 8;
    frag_b16 xa[4];
#pragma unroll
    for (int ks = 0; ks < 4; ++ks) {
        float4 lo = *(const float4*)(xrow + ks * 32);
        float4 hi = *(const float4*)(xrow + ks * 32 + 4);
        union { frag_b16 f; frag_i4 i; } u;
        u.i[0] = pk_bf16(lo.x, lo.y);
        u.i[1] = pk_bf16(lo.z, lo.w);
        u.i[2] = pk_bf16(hi.x, hi.y);
        u.i[3] = pk_bf16(hi.z, hi.w);
        xa[ks] = u.f;
    }

    __syncthreads();

    if (row0 < N_NODES) {
        f32x4 acc[8];
#pragma unroll
        for (int t = 0; t < 8; ++t) acc[t] = (f32x4){0.f, 0.f, 0.f, 0.f};

#pragma unroll
        for (int t = 0; t < 8; ++t) {
            const unsigned short* bp = &wt_lds[(t * 16 + m) * WT_STRIDE + q * 8];
#pragma unroll
            for (int ks = 0; ks < 4; ++ks) {
                frag_b16 wfrag = *(const frag_b16*)(bp + ks * 32);
                acc[t] = __builtin_amdgcn_mfma_f32_16x16x32_bf16(wfrag, xa[ks], acc[t], 0, 0, 0);
            }
        }

        long node = row0 + m;
        if (node < N_NODES) {
            unsigned short* srow = support + node * 128;
#pragma unroll
            for (int t = 0; t < 8; ++t) {
                int2 pk;
                pk.x = pk_bf16(acc[t][0], acc[t][1]);
                pk.y = pk_bf16(acc[t][2], acc[t][3]);
                *(int2*)(srow + t * 16 + q * 4) = pk;
            }
        }
    }
}

// ---------------------------------------------------------------------------
// Fused aggregation. Block = 128 thr = 2 waves = 1 output node.
// Wave w handles frames [7w, 7w+6]; lane owns features {2*lane, 2*lane+1}
// (one dword gather = full 256B support row per wave per edge).
// Phase 1: stage (col,val) of all 7 segments into LDS (coalesced, all loads
// independent). Phase 2: per frame, 8 gathers in flight per waitcnt, cols
// from LDS broadcast. Phase 3: cross-wave max + in-wave log_softmax.
// Per-frame summation order identical to reference segment order.
// ---------------------------------------------------------------------------
__global__ __launch_bounds__(128) void agg_kernel(
        const unsigned short* __restrict__ support, const float* __restrict__ b,
        const float* __restrict__ edge_val, const int* __restrict__ edge_col,
        const int* __restrict__ row_ptr, float* __restrict__ out) {
    __shared__ int   segStart[2][8];
    __shared__ int   segOff[2][8];
    __shared__ int   eCol[2][CAP];
    __shared__ float eVal[2][CAP];
    __shared__ float xch[2][64][2];

    const int i = blockIdx.x;
    const int lane = threadIdx.x & 63;
    const int w = threadIdx.x >> 6;
    const unsigned int* sup32 = (const unsigned int*)support;

    // --- segment scan: lane f (<7) loads its frame's CSR range, wave-scan ---
    int a = 0, len = 0;
    if (lane < 7) {
        int n = (w * 7 + lane) * NODES_PER_FRAME + i;
        a = row_ptr[n];
        len = row_ptr[n + 1] - a;
    }
    int off = 0;
#pragma unroll
    for (int f2 = 0; f2 < 7; ++f2) {
        int L2 = __shfl(len, f2);
        if (f2 < lane) off += L2;
    }
    if (lane < 7) { segStart[w][lane] = a; segOff[w][lane] = off; }
    if (lane == 6) segOff[w][7] = off + len;
    __syncthreads();

    // --- stage edges into LDS (all global loads independent) ---
#pragma unroll 1
    for (int f = 0; f < 7; ++f) {
        int g = segStart[w][f], s = segOff[w][f], L = segOff[w][f + 1] - s;
        for (int j = lane; j < L; j += 64) {
            int d = s + j;
            if (d < CAP) { eCol[w][d] = edge_col[g + j]; eVal[w][d] = edge_val[g + j]; }
        }
    }
    __syncthreads();

    const float2 bb = *(const float2*)&b[lane * 2];
    float2 mx = make_float2(0.f, 0.f);                 // relu => max >= 0

#pragma unroll 1
    for (int f = 0; f < 7; ++f) {
        int g = segStart[w][f], s = segOff[w][f], L = segOff[w][f + 1] - s;
        float ax = 0.f, ay = 0.f;
        int j = 0;
        for (; j + 8 <= L; j += 8) {
            int cols[8]; float vals[8];
#pragma unroll
            for (int u = 0; u < 8; ++u) {
                int d = s + j + u;
                if (d < CAP) { cols[u] = eCol[w][d]; vals[u] = eVal[w][d]; }
                else         { cols[u] = edge_col[g + j + u]; vals[u] = edge_val[g + j + u]; }
            }
            unsigned int sv[8];
#pragma unroll
            for (int u = 0; u < 8; ++u) sv[u] = sup32[(cols[u] << 6) | lane];
#pragma unroll
            for (int u = 0; u < 8; ++u) {
                float2 s2 = bf2x2(sv[u]);
                ax = fmaf(vals[u], s2.x, ax);
                ay = fmaf(vals[u], s2.y, ay);
            }
        }
        for (; j < L; ++j) {
            int d = s + j; int c; float v;
            if (d < CAP) { c = eCol[w][d]; v = eVal[w][d]; }
            else         { c = edge_col[g + j]; v = edge_val[g + j]; }
            float2 s2 = bf2x2(sup32[(c << 6) | lane]);
            ax = fmaf(v, s2.x, ax);
            ay = fmaf(v, s2.y, ay);
        }
        float hx = ax + bb.x, hy = ay + bb.y;
        mx.x = fmaxf(mx.x, hx > 0.f ? hx : 0.f);
        mx.y = fmaxf(mx.y, hy > 0.f ? hy : 0.f);
    }

    // --- cross-wave max exchange ---
    xch[w][lane][0] = mx.x;
    xch[w][lane][1] = mx.y;
    __syncthreads();
    float ox = fmaxf(xch[0][lane][0], xch[1][lane][0]);
    float oy = fmaxf(xch[0][lane][1], xch[1][lane][1]);

    // --- in-wave log_softmax over 128 features (both waves redundant) ---
    float M = fmaxf(ox, oy);
#pragma unroll
    for (int o = 32; o >= 1; o >>= 1) M = fmaxf(M, __shfl_xor(M, o));
    float S = __expf(ox - M) + __expf(oy - M);
#pragma unroll
    for (int o = 32; o >= 1; o >>= 1) S += __shfl_xor(S, o);

    if (w == 0) {
        float ls = __logf(S);
        float2 o2 = make_float2((ox - M) - ls, (oy - M) - ls);
        *(float2*)&out[i * 128 + lane * 2] = o2;
    }
}

// ---------------------------------------------------------------------------
extern "C" void kernel_launch(void* const* d_in, const int* in_sizes, int n_in,
                              void* d_out, int out_size, void* d_ws, size_t ws_size,
                              hipStream_t stream) {
    const float* x        = (const float*)d_in[0];
    const float* W        = (const float*)d_in[1];
    const float* b        = (const float*)d_in[2];
    const float* edge_val = (const float*)d_in[3];
    const int*   edge_row = (const int*)d_in[4];
    const int*   edge_col = (const int*)d_in[5];
    float* out = (float*)d_out;

    char* ws = (char*)d_ws;
    unsigned short* support = (unsigned short*)ws;                  // 35,840,000 B
    unsigned short* WT      = (unsigned short*)(ws + 35840000);     //     32,768 B
    int*            row_ptr = (int*)(ws + 35840000 + 32768);        //    560,004 B

    convert_wt<<<64, 256, 0, stream>>>(W, WT);
    build_row_ptr<<<(N_EDGES + 255) / 256, 256, 0, stream>>>(edge_row, row_ptr);
    gemm_kernel<<<(N_NODES + 63) / 64, 256, 0, stream>>>(x, WT, support);
    agg_kernel<<<NODES_PER_FRAME, 128, 0, stream>>>(support, b, edge_val, edge_col, row_ptr, out);
}

// Round 4
// 221.438 us; speedup vs baseline: 1.8454x; 1.1043x over previous
//
#include <hip/hip_runtime.h>
#include <hip/hip_bf16.h>

#define N_NODES 140000
#define N_EDGES 2240000
#define NFEAT 128
#define NHID 128
#define N_FRAMES 14
#define NODES_PER_FRAME 10000
#define CAP 352            // int2 LDS slots per wave (7 frames padded to x8; avg 140, max<250)

typedef __attribute__((ext_vector_type(8))) short frag_b16;
typedef __attribute__((ext_vector_type(4))) int frag_i4;
typedef __attribute__((ext_vector_type(4))) float f32x4;

__device__ __forceinline__ unsigned short f2bf(float f) {
    union { float f; unsigned int u; } v; v.f = f;
    unsigned int r = v.u + 0x7fffu + ((v.u >> 16) & 1u);   // RNE
    return (unsigned short)(r >> 16);
}
__device__ __forceinline__ int pk_bf16(float a, float b) {
    union { __hip_bfloat162 h; int i; } u;
    u.h = __float22bfloat162_rn(make_float2(a, b));        // v_cvt_pk_bf16_f32
    return u.i;
}
__device__ __forceinline__ float2 bf2x2(unsigned int u) {
    union { unsigned int u; float f; } lo, hi;
    lo.u = u << 16;
    hi.u = u & 0xffff0000u;
    return make_float2(lo.f, hi.f);
}

// ---------------------------------------------------------------------------
// Prep (merged): W^T bf16 conversion + CSR row offsets from sorted COO rows.
// Grid sized for N_EDGES; first 16384 threads also handle the WT transpose.
// ---------------------------------------------------------------------------
__global__ void prep_kernel(const float* __restrict__ W, unsigned short* __restrict__ WT,
                            const int* __restrict__ edge_row, int* __restrict__ row_ptr) {
    int e = blockIdx.x * blockDim.x + threadIdx.x;
    if (e < NFEAT * NHID) {
        int k = e >> 7, n = e & 127;
        WT[n * 128 + k] = f2bf(W[e]);
    }
    if (e < N_EDGES) {
        int r = edge_row[e];
        int prev = (e == 0) ? -1 : edge_row[e - 1];
        for (int q = prev + 1; q <= r; ++q) row_ptr[q] = e;
        if (e == N_EDGES - 1) {
            for (int q = r + 1; q <= N_NODES; ++q) row_ptr[q] = N_EDGES;
        }
    }
}

// ---------------------------------------------------------------------------
// GEMM: support_bf16 = bf16(x @ W), mfma_f32_16x16x32_bf16, operands swapped
// (A = W^T frag, B = x frag) so each lane's 4 acc regs = 4 consecutive
// features of one node -> packed 8B stores.  (unchanged from round 3)
// ---------------------------------------------------------------------------
#define WT_STRIDE 136

__global__ __launch_bounds__(256) void gemm_kernel(
        const float* __restrict__ x, const unsigned short* __restrict__ WT,
        unsigned short* __restrict__ support) {
    __shared__ unsigned short wt_lds[128 * WT_STRIDE];

    const uint4* WTv = (const uint4*)WT;               // 2048 uint4
    for (int idx = threadIdx.x; idx < 2048; idx += 256) {
        uint4 d = WTv[idx];
        int elem = idx << 3;
        int n = elem >> 7, k = elem & 127;
        *(uint4*)&wt_lds[n * WT_STRIDE + k] = d;
    }

    int wave = threadIdx.x >> 6;
    int lane = threadIdx.x & 63;
    int m = lane & 15;
    int q = lane >> 4;

    long row0 = (long)blockIdx.x * 64 + wave * 16;

    int arow = (int)row0 + m;
    if (arow >= N_NODES) arow = N_NODES - 1;
    const float* xrow = x + (long)arow * 128 + q * 8;
    frag_b16 xa[4];
#pragma unroll
    for (int ks = 0; ks < 4; ++ks) {
        float4 lo = *(const float4*)(xrow + ks * 32);
        float4 hi = *(const float4*)(xrow + ks * 32 + 4);
        union { frag_b16 f; frag_i4 i; } u;
        u.i[0] = pk_bf16(lo.x, lo.y);
        u.i[1] = pk_bf16(lo.z, lo.w);
        u.i[2] = pk_bf16(hi.x, hi.y);
        u.i[3] = pk_bf16(hi.z, hi.w);
        xa[ks] = u.f;
    }

    __syncthreads();

    if (row0 < N_NODES) {
        f32x4 acc[8];
#pragma unroll
        for (int t = 0; t < 8; ++t) acc[t] = (f32x4){0.f, 0.f, 0.f, 0.f};

#pragma unroll
        for (int t = 0; t < 8; ++t) {
            const unsigned short* bp = &wt_lds[(t * 16 + m) * WT_STRIDE + q * 8];
#pragma unroll
            for (int ks = 0; ks < 4; ++ks) {
                frag_b16 wfrag = *(const frag_b16*)(bp + ks * 32);
                acc[t] = __builtin_amdgcn_mfma_f32_16x16x32_bf16(wfrag, xa[ks], acc[t], 0, 0, 0);
            }
        }

        long node = row0 + m;
        if (node < N_NODES) {
            unsigned short* srow = support + node * 128;
#pragma unroll
            for (int t = 0; t < 8; ++t) {
                int2 pk;
                pk.x = pk_bf16(acc[t][0], acc[t][1]);
                pk.y = pk_bf16(acc[t][2], acc[t][3]);
                *(int2*)(srow + t * 16 + q * 4) = pk;
            }
        }
    }
}

// ---------------------------------------------------------------------------
// Fused aggregation. Block = 128 thr = 2 waves = 1 output node.
// Wave w: frames [7w, 7w+6]; lane owns features {2*lane, 2*lane+1}.
// (col,val) staged interleaved (int2) in LDS, each frame segment PADDED to a
// multiple of 8 with {0, 0.0f} (fma(0,s,a)==a bit-exact) -> inner loop is
// pure 8-groups: no tails, no per-element predicates. Wave-uniform fallback
// to global reads if a wave's padded total exceeds CAP (never for this data).
// ---------------------------------------------------------------------------
__global__ __launch_bounds__(128) void agg_kernel(
        const unsigned short* __restrict__ support, const float* __restrict__ b,
        const float* __restrict__ edge_val, const int* __restrict__ edge_col,
        const int* __restrict__ row_ptr, float* __restrict__ out) {
    __shared__ int   segStart[2][8];
    __shared__ int   segLen[2][8];
    __shared__ int   segOff[2][8];
    __shared__ int2  eBuf[2][CAP];
    __shared__ float xch[2][64][2];

    const int i = blockIdx.x;
    const int lane = threadIdx.x & 63;
    const int w = threadIdx.x >> 6;
    const char* supB = (const char*)support;
    const unsigned lane4 = (unsigned)lane * 4u;

    // --- segment scan (padded-to-8 exclusive scan across 7 frames) ---
    int a = 0, len = 0;
    if (lane < 7) {
        int n = (w * 7 + lane) * NODES_PER_FRAME + i;
        a = row_ptr[n];
        len = row_ptr[n + 1] - a;
    }
    int len8 = (len + 7) & ~7;
    int off = 0;
#pragma unroll
    for (int f2 = 0; f2 < 7; ++f2) {
        int L2 = __shfl(len8, f2);
        if (f2 < lane) off += L2;
    }
    if (lane < 7) { segStart[w][lane] = a; segLen[w][lane] = len; segOff[w][lane] = off; }
    if (lane == 6) segOff[w][7] = off + len8;
    __syncthreads();

    const bool fit = segOff[w][7] <= CAP;              // wave-uniform

    // --- stage edges into LDS, zero-padded per frame ---
    if (fit) {
#pragma unroll 1
        for (int f = 0; f < 7; ++f) {
            int g = segStart[w][f], s = segOff[w][f], L = segLen[w][f];
            int L8 = (L + 7) & ~7;
            for (int j = lane; j < L8; j += 64) {
                int2 v;
                if (j < L) { v.x = edge_col[g + j]; v.y = __float_as_int(edge_val[g + j]); }
                else       { v.x = 0; v.y = 0; }
                eBuf[w][s + j] = v;
            }
        }
    }
    __syncthreads();

    const float2 bb = *(const float2*)&b[lane * 2];
    float2 mx = make_float2(0.f, 0.f);                 // relu => max >= 0

    if (fit) {
#pragma unroll 1
        for (int f = 0; f < 7; ++f) {
            int s = segOff[w][f];
            int e8 = s + ((segLen[w][f] + 7) & ~7);
            float ax = 0.f, ay = 0.f;
            for (int j = s; j < e8; j += 8) {
                unsigned sv[8];
                float vv[8];
#pragma unroll
                for (int u = 0; u < 8; ++u) {
                    int2 ed = eBuf[w][j + u];
                    unsigned o = ((unsigned)ed.x << 8) + lane4;
                    sv[u] = *(const unsigned*)(supB + o);
                    vv[u] = __int_as_float(ed.y);
                }
#pragma unroll
                for (int u = 0; u < 8; ++u) {
                    float2 s2 = bf2x2(sv[u]);
                    ax = fmaf(vv[u], s2.x, ax);
                    ay = fmaf(vv[u], s2.y, ay);
                }
            }
            float hx = ax + bb.x, hy = ay + bb.y;
            mx.x = fmaxf(mx.x, hx > 0.f ? hx : 0.f);
            mx.y = fmaxf(mx.y, hy > 0.f ? hy : 0.f);
        }
    } else {
        // safety fallback: direct global reads (identical per-frame order)
#pragma unroll 1
        for (int f = 0; f < 7; ++f) {
            int g = segStart[w][f], L = segLen[w][f];
            float ax = 0.f, ay = 0.f;
            for (int j = 0; j < L; ++j) {
                int c = edge_col[g + j];
                float v = edge_val[g + j];
                float2 s2 = bf2x2(*(const unsigned*)(supB + (((unsigned)c << 8) + lane4)));
                ax = fmaf(v, s2.x, ax);
                ay = fmaf(v, s2.y, ay);
            }
            float hx = ax + bb.x, hy = ay + bb.y;
            mx.x = fmaxf(mx.x, hx > 0.f ? hx : 0.f);
            mx.y = fmaxf(mx.y, hy > 0.f ? hy : 0.f);
        }
    }

    // --- cross-wave max exchange ---
    xch[w][lane][0] = mx.x;
    xch[w][lane][1] = mx.y;
    __syncthreads();
    float ox = fmaxf(xch[0][lane][0], xch[1][lane][0]);
    float oy = fmaxf(xch[0][lane][1], xch[1][lane][1]);

    // --- in-wave log_softmax over 128 features ---
    float M = fmaxf(ox, oy);
#pragma unroll
    for (int o = 32; o >= 1; o >>= 1) M = fmaxf(M, __shfl_xor(M, o));
    float S = __expf(ox - M) + __expf(oy - M);
#pragma unroll
    for (int o = 32; o >= 1; o >>= 1) S += __shfl_xor(S, o);

    if (w == 0) {
        float ls = __logf(S);
        float2 o2 = make_float2((ox - M) - ls, (oy - M) - ls);
        *(float2*)&out[i * 128 + lane * 2] = o2;
    }
}

// ---------------------------------------------------------------------------
extern "C" void kernel_launch(void* const* d_in, const int* in_sizes, int n_in,
                              void* d_out, int out_size, void* d_ws, size_t ws_size,
                              hipStream_t stream) {
    const float* x        = (const float*)d_in[0];
    const float* W        = (const float*)d_in[1];
    const float* b        = (const float*)d_in[2];
    const float* edge_val = (const float*)d_in[3];
    const int*   edge_row = (const int*)d_in[4];
    const int*   edge_col = (const int*)d_in[5];
    float* out = (float*)d_out;

    char* ws = (char*)d_ws;
    unsigned short* support = (unsigned short*)ws;                  // 35,840,000 B
    unsigned short* WT      = (unsigned short*)(ws + 35840000);     //     32,768 B
    int*            row_ptr = (int*)(ws + 35840000 + 32768);        //    560,004 B

    prep_kernel<<<(N_EDGES + 255) / 256, 256, 0, stream>>>(W, WT, edge_row, row_ptr);
    gemm_kernel<<<(N_NODES + 63) / 64, 256, 0, stream>>>(x, WT, support);
    agg_kernel<<<NODES_PER_FRAME, 128, 0, stream>>>(support, b, edge_val, edge_col, row_ptr, out);
}